// Round 3
// baseline (215.748 us; speedup 1.0000x reference)
//
#include <hip/hip_runtime.h>

// Depthwise causal conv1d, k=3.
// x: (8, 768, 4096) fp32, weight: (768, 1, 3) fp32, y: (8, 768, 4096) fp32.
// y[n,c,t] = w[c,0]*x[t-2] + w[c,1]*x[t-1] + w[c,2]*x[t], zeros left of t=0.
//
// Memory-bound: ~201 MB total traffic -> floor ~30 us at 6.8 TB/s (proven by
// the harness fill kernel on this very buffer).
// v4 = v3 with nontemporal REMOVED from loads (kept on stores). x is
// L2/LLC-resident (re-poison fill just wrote it; 100 MB << 256 MB LLC);
// nt loads defeated cache retention and made the kernel latency-bound at
// 2.65 TB/s (78 us, VALUBusy 2.4%). Plain loads hit L2 at ~200 cy, which
// 4 outstanding dwordx4/thread can cover. Stores stay nt: y is write-only
// streaming, evict-first is the right policy.

#define CONV_L 4096
#define CONV_C 768

typedef float vfloat4 __attribute__((ext_vector_type(4)));

__global__ __launch_bounds__(256) void dwconv1d_k3_x4(
    const float* __restrict__ x,
    const float* __restrict__ w,
    float* __restrict__ y)
{
    const int row = blockIdx.x;          // 0..6143, block-uniform
    const int c   = row % CONV_C;        // uniform -> weight loads are scalar

    const float w0 = w[c * 3 + 0];
    const float w1 = w[c * 3 + 1];
    const float w2 = w[c * 3 + 2];

    const float* xrow = x + (size_t)row * CONV_L;
    float*       yrow = y + (size_t)row * CONV_L;

    const int t = threadIdx.x;           // thread covers floats [16t, 16t+16)
    const float4* xin = (const float4*)xrow + (t << 2);

    // 4 independent 16B loads -> 4 outstanding VMEM ops per lane (plain,
    // cache-retaining: x is hot in L2/LLC from the re-poison fill).
    const float4 c0 = xin[0];
    const float4 c1 = xin[1];
    const float4 c2 = xin[2];
    const float4 c3 = xin[3];

    // History for the first float4 comes from the previous lane's last float4.
    float xm1 = __shfl_up(c3.w, 1);      // x[16t-1]
    float xm2 = __shfl_up(c3.z, 1);      // x[16t-2]
    if ((t & 63) == 0) {
        if (t == 0) {
            xm1 = 0.0f; xm2 = 0.0f;      // causal left edge of the row
        } else {
            // (16t-2)*4 bytes is 8B-aligned -> single dwordx2.
            const float2 h = *(const float2*)(xrow + (t << 4) - 2);
            xm2 = h.x; xm1 = h.y;
        }
    }

    vfloat4 o0, o1, o2, o3;
    o0.x = w0 * xm2  + w1 * xm1  + w2 * c0.x;
    o0.y = w0 * xm1  + w1 * c0.x + w2 * c0.y;
    o0.z = w0 * c0.x + w1 * c0.y + w2 * c0.z;
    o0.w = w0 * c0.y + w1 * c0.z + w2 * c0.w;

    o1.x = w0 * c0.z + w1 * c0.w + w2 * c1.x;
    o1.y = w0 * c0.w + w1 * c1.x + w2 * c1.y;
    o1.z = w0 * c1.x + w1 * c1.y + w2 * c1.z;
    o1.w = w0 * c1.y + w1 * c1.z + w2 * c1.w;

    o2.x = w0 * c1.z + w1 * c1.w + w2 * c2.x;
    o2.y = w0 * c1.w + w1 * c2.x + w2 * c2.y;
    o2.z = w0 * c2.x + w1 * c2.y + w2 * c2.z;
    o2.w = w0 * c2.y + w1 * c2.z + w2 * c2.w;

    o3.x = w0 * c2.z + w1 * c2.w + w2 * c3.x;
    o3.y = w0 * c2.w + w1 * c3.x + w2 * c3.y;
    o3.z = w0 * c3.x + w1 * c3.y + w2 * c3.z;
    o3.w = w0 * c3.y + w1 * c3.z + w2 * c3.w;

    vfloat4* yout = (vfloat4*)yrow + (t << 2);
    __builtin_nontemporal_store(o0, yout + 0);
    __builtin_nontemporal_store(o1, yout + 1);
    __builtin_nontemporal_store(o2, yout + 2);
    __builtin_nontemporal_store(o3, yout + 3);
}

extern "C" void kernel_launch(void* const* d_in, const int* in_sizes, int n_in,
                              void* d_out, int out_size, void* d_ws, size_t ws_size,
                              hipStream_t stream)
{
    const float* x = (const float*)d_in[0];
    const float* w = (const float*)d_in[1];
    float* y = (float*)d_out;

    const int rows = out_size / CONV_L;   // out_size is ELEMENTS: 8*768 = 6144
    dwconv1d_k3_x4<<<rows, 256, 0, stream>>>(x, w, y);
}

// Round 4
// 174.809 us; speedup vs baseline: 1.2342x; 1.2342x over previous
//
#include <hip/hip_runtime.h>

// Depthwise causal conv1d, k=3.
// x: (8, 768, 4096) fp32, weight: (768, 1, 3) fp32, y: (8, 768, 4096) fp32.
// y[n,c,t] = w[c,0]*x[t-2] + w[c,1]*x[t-1] + w[c,2]*x[t], zeros left of t=0.
//
// v5: one block per row; thread t owns float4 indices {t, t+256, t+512, t+768}.
// Every load INSTRUCTION is lane-contiguous (64 lanes x 16 B = 1 KB segment,
// fully-used 128 B lines) -- v2/v3/v4's 64 B/thread layout gave each load a
// 64 B inter-lane stride (25% line utilization per request, 4x TA/L2 request
// amplification) and regressed 54 -> 78-97 us. v5 keeps v1's perfect
// coalescing while amortizing per-wave setup (kernarg s_loads, weight loads)
// over 4x the bytes and keeping 4 loads in flight per thread.
// History per segment comes from the previous lane of the SAME segment
// (exactly v1's shfl pattern); wave-lead lanes reload a float2 from global.
// Loads plain (x is L2/LLC-warm; v1-proven), stores nontemporal (y is
// write-only streaming; v1-proven).

#define CONV_L 4096
#define CONV_C 768

typedef float vfloat4 __attribute__((ext_vector_type(4)));

__global__ __launch_bounds__(256) void dwconv1d_k3_seg(
    const float* __restrict__ x,
    const float* __restrict__ w,
    float* __restrict__ y)
{
    const int row = blockIdx.x;          // 0..6143, block-uniform
    const int c   = row % CONV_C;        // uniform -> weight loads are scalar

    const float w0 = w[c * 3 + 0];
    const float w1 = w[c * 3 + 1];
    const float w2 = w[c * 3 + 2];

    const float* xrow = x + (size_t)row * CONV_L;
    float*       yrow = y + (size_t)row * CONV_L;

    const int t = threadIdx.x;           // float4 indices t + 256*j, j=0..3

    // 4 independent, each lane-contiguous (1 KB/wave-instruction) loads.
    const float4* xin = (const float4*)xrow;
    const float4 c0 = xin[t      ];
    const float4 c1 = xin[t + 256];
    const float4 c2 = xin[t + 512];
    const float4 c3 = xin[t + 768];

    // Per-segment history from the previous lane's float4 of the SAME segment.
    float m1_0 = __shfl_up(c0.w, 1), m2_0 = __shfl_up(c0.z, 1);
    float m1_1 = __shfl_up(c1.w, 1), m2_1 = __shfl_up(c1.z, 1);
    float m1_2 = __shfl_up(c2.w, 1), m2_2 = __shfl_up(c2.z, 1);
    float m1_3 = __shfl_up(c3.w, 1), m2_3 = __shfl_up(c3.z, 1);

    if ((t & 63) == 0) {
        // Segment j starts at float 4*(t+256j); history = floats 4p-2, 4p-1.
        if (t == 0) {
            m1_0 = 0.0f; m2_0 = 0.0f;    // causal left edge of the row
        } else {
            const float2 h = *(const float2*)(xrow + (t << 2) - 2);
            m2_0 = h.x; m1_0 = h.y;
        }
        const float2 h1 = *(const float2*)(xrow + ((t + 256) << 2) - 2);
        m2_1 = h1.x; m1_1 = h1.y;
        const float2 h2 = *(const float2*)(xrow + ((t + 512) << 2) - 2);
        m2_2 = h2.x; m1_2 = h2.y;
        const float2 h3 = *(const float2*)(xrow + ((t + 768) << 2) - 2);
        m2_3 = h3.x; m1_3 = h3.y;
    }

    vfloat4* yout = (vfloat4*)yrow;
    vfloat4 o;

#define CONV_SEG(cc, m1, m2, off)                      \
    o.x = w0 * (m2)  + w1 * (m1)  + w2 * (cc).x;       \
    o.y = w0 * (m1)  + w1 * (cc).x + w2 * (cc).y;      \
    o.z = w0 * (cc).x + w1 * (cc).y + w2 * (cc).z;     \
    o.w = w0 * (cc).y + w1 * (cc).z + w2 * (cc).w;     \
    __builtin_nontemporal_store(o, yout + t + (off));

    CONV_SEG(c0, m1_0, m2_0, 0)
    CONV_SEG(c1, m1_1, m2_1, 256)
    CONV_SEG(c2, m1_2, m2_2, 512)
    CONV_SEG(c3, m1_3, m2_3, 768)
#undef CONV_SEG
}

extern "C" void kernel_launch(void* const* d_in, const int* in_sizes, int n_in,
                              void* d_out, int out_size, void* d_ws, size_t ws_size,
                              hipStream_t stream)
{
    const float* x = (const float*)d_in[0];
    const float* w = (const float*)d_in[1];
    float* y = (float*)d_out;

    const int rows = out_size / CONV_L;   // out_size is ELEMENTS: 8*768 = 6144
    dwconv1d_k3_seg<<<rows, 256, 0, stream>>>(x, w, y);
}